// Round 3
// baseline (401.069 us; speedup 1.0000x reference)
//
#include <hip/hip_runtime.h>
#include <math.h>

#define NN 100000   // nodes
#define DD 128      // dim
#define MM 3        // metapaths
#define EE 400000   // edges per metapath
#define CAP 32      // max bucketed degree (Poisson(4): P(deg>=32) ~ 1e-17)

// ---------------------------------------------------------------------------
// ws layout (bytes):
//   l    [NN][128] f32   51.2 MB
//   beta [NN][4]   f32    1.6 MB
//   deg  [MM][NN]  i32    1.2 MB
//   lst  [MM][NN][CAP] i32 38.4 MB
//   flag [1] i32
// total ~92.5 MB
// ---------------------------------------------------------------------------

// Detect whether edge_index arrived as int64 (odd 32-bit words all zero) or int32.
__global__ void k_detect(const int* __restrict__ ei, int* __restrict__ flag) {
  if (threadIdx.x == 0 && blockIdx.x == 0) {
    int orsum = 0;
    for (int i = 0; i < 64; ++i) orsum |= ei[2 * i + 1];
    flag[0] = (orsum == 0) ? 1 : 0;
  }
}

// Fused: l = x@Wl^T + bl ; beta = softmax(x@Wc^T + bc) ; deg = 0
// block = 256 (4 waves), 64 rows per block. Wl staged transposed in LDS in
// two k-halves (keeps LDS at ~69 KB -> 2 blocks/CU).
__global__ __launch_bounds__(256, 2)
void k_prep(const float* __restrict__ x,
            const float* __restrict__ Wl,
            const float* __restrict__ bl,
            const float* __restrict__ Wc,
            const float* __restrict__ bc,
            float* __restrict__ l_out,
            float* __restrict__ beta_out,
            int* __restrict__ deg) {
  __shared__ float xs[64][132];   // +4 pad: bank-spread, keeps 16B alignment
  __shared__ float wlt[64][130];  // transposed half of Wl: wlt[kk][j]
  __shared__ float wcs[4][132];
  __shared__ float bcs[4];
  const int t = threadIdx.x;
  const int r0 = blockIdx.x * 64;

  // stage x tile (64 rows x 128), coalesced float4
  #pragma unroll
  for (int i = 0; i < 8; ++i) {
    int f4 = t + 256 * i;         // 0..2047
    int row = f4 >> 5;
    int kq = f4 & 31;
    int gr = r0 + row; if (gr >= NN) gr = NN - 1;   // clamp; stores guarded
    float4 v = *reinterpret_cast<const float4*>(&x[(size_t)gr * DD + kq * 4]);
    *reinterpret_cast<float4*>(&xs[row][kq * 4]) = v;
  }
  if (t < 128) {                  // Wc: 4x128 floats = 128 float4
    int m = t >> 5, kq = t & 31;
    float4 v = *reinterpret_cast<const float4*>(&Wc[m * DD + kq * 4]);
    *reinterpret_cast<float4*>(&wcs[m][kq * 4]) = v;
  }
  if (t < 4) bcs[t] = bc[t];
  if (t < 192) {                  // zero degree counters for this row range
    int m = t >> 6;
    int n = r0 + (t & 63);
    if (n < NN) deg[m * NN + n] = 0;
  }

  const int w = t >> 6;           // wave id: rows w*16..w*16+15
  const int lane = t & 63;        // cols 2*lane, 2*lane+1
  float acc0[16], acc1[16];
  #pragma unroll
  for (int r = 0; r < 16; ++r) { acc0[r] = 0.f; acc1[r] = 0.f; }

  for (int h = 0; h < 2; ++h) {   // two k-halves of Wl
    __syncthreads();              // (h=0: xs ready; h=1: wlt reuse safe)
    #pragma unroll
    for (int i = 0; i < 8; ++i) { // stage Wl[j][64h..64h+63] transposed
      int f4 = t + 256 * i;       // 0..2047
      int j = f4 >> 4;            // 0..127
      int kq = f4 & 15;           // 0..15
      float4 v = *reinterpret_cast<const float4*>(&Wl[j * DD + h * 64 + kq * 4]);
      wlt[kq * 4 + 0][j] = v.x;
      wlt[kq * 4 + 1][j] = v.y;
      wlt[kq * 4 + 2][j] = v.z;
      wlt[kq * 4 + 3][j] = v.w;
    }
    __syncthreads();
    #pragma unroll
    for (int kq = 0; kq < 16; ++kq) {
      // lane's two output columns; lanes l and l+32 alias banks 2-way (free)
      float2 w0 = *reinterpret_cast<const float2*>(&wlt[kq * 4 + 0][lane * 2]);
      float2 w1 = *reinterpret_cast<const float2*>(&wlt[kq * 4 + 1][lane * 2]);
      float2 w2 = *reinterpret_cast<const float2*>(&wlt[kq * 4 + 2][lane * 2]);
      float2 w3 = *reinterpret_cast<const float2*>(&wlt[kq * 4 + 3][lane * 2]);
      #pragma unroll
      for (int r = 0; r < 16; ++r) {
        float4 xv = *reinterpret_cast<const float4*>(&xs[w * 16 + r][h * 64 + kq * 4]);
        acc0[r] += xv.x * w0.x; acc0[r] += xv.y * w1.x;
        acc0[r] += xv.z * w2.x; acc0[r] += xv.w * w3.x;
        acc1[r] += xv.x * w0.y; acc1[r] += xv.y * w1.y;
        acc1[r] += xv.z * w2.y; acc1[r] += xv.w * w3.y;
      }
    }
  }

  // bias + store l (float2 per lane -> 512B contiguous per wave-row)
  float2 blv = *reinterpret_cast<const float2*>(&bl[lane * 2]);
  #pragma unroll
  for (int r = 0; r < 16; ++r) {
    int row = r0 + w * 16 + r;
    if (row < NN) {
      float2 o; o.x = acc0[r] + blv.x; o.y = acc1[r] + blv.y;
      *reinterpret_cast<float2*>(&l_out[(size_t)row * DD + lane * 2]) = o;
    }
  }

  // beta: 64 rows x 4 logits == 256 threads; softmax across 4-lane groups
  {
    int r = t >> 2, m = t & 3;
    float lg = bcs[m];
    for (int k = 0; k < 128; ++k) lg += xs[r][k] * wcs[m][k];
    float mx = fmaxf(lg, __shfl_xor(lg, 1, 4));
    mx = fmaxf(mx, __shfl_xor(mx, 2, 4));
    float e = __expf(lg - mx);
    float s = e + __shfl_xor(e, 1, 4);
    s += __shfl_xor(s, 2, 4);
    int n = r0 + r;
    if (n < NN) beta_out[n * 4 + m] = e / s;
  }
}

// Bucket edges by destination: deg[m][idx]++, lst[m][idx][slot] = nbr
__global__ __launch_bounds__(256)
void k_scatter(const int* __restrict__ ei, const int* __restrict__ flag,
               int* __restrict__ deg, int* __restrict__ lst) {
  int i = blockIdx.x * 256 + threadIdx.x;
  if (i >= MM * EE) return;
  int m = i / EE, e = i - m * EE;
  size_t pi = (size_t)m * 2 * EE + e;    // idx position
  size_t pn = pi + EE;                   // nbr position
  int idx, nbr;
  if (flag[0]) { idx = ei[2 * pi]; nbr = ei[2 * pn]; }  // int64 input
  else         { idx = ei[pi];     nbr = ei[pn];     }  // int32 input
  int slot = atomicAdd(&deg[m * NN + idx], 1);
  if (slot < CAP) lst[((size_t)m * NN + idx) * CAP + slot] = nbr;
}

// Fused per-node aggregation + relation mix + relu.
// 16 threads per node, 8 channels each. Online exp-aggregation, no atomics:
//   rel = sum_e l[nbr]*exp(u) / (sum_e exp(u) + 1e-16),  u = l[nbr]*al*s
// (r-projection term cancels in segment softmax; max-subtraction unnecessary
//  since |u| <~ 1.5)
__global__ __launch_bounds__(256, 4)
void k_agg(const float* __restrict__ l, const float* __restrict__ beta,
           const int* __restrict__ deg, const int* __restrict__ lst,
           const float* __restrict__ attn_l, const float* __restrict__ sharpen,
           float* __restrict__ out) {
  int tid = blockIdx.x * 256 + threadIdx.x;
  int node = tid >> 4;
  if (node >= NN) return;
  int ch0 = (tid & 15) << 3;   // 8 channels per thread

  float ls[8], acc[8];
  {
    const float* lp = l + (size_t)node * DD + ch0;
    *reinterpret_cast<float4*>(&ls[0]) = *reinterpret_cast<const float4*>(&lp[0]);
    *reinterpret_cast<float4*>(&ls[4]) = *reinterpret_cast<const float4*>(&lp[4]);
  }
  float4 bt = *reinterpret_cast<const float4*>(&beta[(size_t)node * 4]);
  #pragma unroll
  for (int i = 0; i < 8; ++i) acc[i] = bt.w * ls[i];   // self relation slot

  #pragma unroll 1
  for (int m = 0; m < MM; ++m) {
    float sm = sharpen[m];
    float al[8];
    {
      const float* ap = attn_l + m * DD + ch0;
      *reinterpret_cast<float4*>(&al[0]) = *reinterpret_cast<const float4*>(&ap[0]);
      *reinterpret_cast<float4*>(&al[4]) = *reinterpret_cast<const float4*>(&ap[4]);
      #pragma unroll
      for (int i = 0; i < 8; ++i) al[i] *= sm;
    }
    float num[8], den[8];
    #pragma unroll
    for (int i = 0; i < 8; ++i) { num[i] = 0.f; den[i] = 0.f; }
    int cnt = deg[(size_t)m * NN + node];
    if (cnt > CAP) cnt = CAP;
    const int* lb = lst + ((size_t)m * NN + node) * CAP;
    for (int s = 0; s < cnt; ++s) {
      int nbr = lb[s];
      const float* np = l + (size_t)nbr * DD + ch0;
      float lv[8];
      *reinterpret_cast<float4*>(&lv[0]) = *reinterpret_cast<const float4*>(&np[0]);
      *reinterpret_cast<float4*>(&lv[4]) = *reinterpret_cast<const float4*>(&np[4]);
      #pragma unroll
      for (int i = 0; i < 8; ++i) {
        float e = __expf(lv[i] * al[i]);
        den[i] += e;
        num[i] += lv[i] * e;
      }
    }
    float bm = (m == 0) ? bt.x : (m == 1) ? bt.y : bt.z;
    #pragma unroll
    for (int i = 0; i < 8; ++i) acc[i] += bm * (num[i] / (den[i] + 1e-16f));
  }

  float* op = out + (size_t)node * DD + ch0;
  #pragma unroll
  for (int i = 0; i < 8; ++i) acc[i] = fmaxf(acc[i], 0.f);
  *reinterpret_cast<float4*>(&op[0]) = *reinterpret_cast<float4*>(&acc[0]);
  *reinterpret_cast<float4*>(&op[4]) = *reinterpret_cast<float4*>(&acc[4]);
}

extern "C" void kernel_launch(void* const* d_in, const int* in_sizes, int n_in,
                              void* d_out, int out_size, void* d_ws, size_t ws_size,
                              hipStream_t stream) {
  const float* x_l     = (const float*)d_in[0];
  // d_in[1] x_r, d_in[5] Wr, d_in[6] br, d_in[10] attn_r: mathematically dead
  // (the r-term is constant within each softmax segment and cancels exactly).
  const int*   ei      = (const int*)d_in[2];
  const float* Wl      = (const float*)d_in[3];
  const float* bl      = (const float*)d_in[4];
  const float* Wc      = (const float*)d_in[7];
  const float* bc      = (const float*)d_in[8];
  const float* attn_l  = (const float*)d_in[9];
  const float* sharpen = (const float*)d_in[11];
  float* out = (float*)d_out;

  float* l    = (float*)d_ws;
  float* beta = l + (size_t)NN * DD;
  int*   deg  = (int*)(beta + (size_t)NN * 4);
  int*   lst  = deg + (size_t)MM * NN;
  int*   flag = lst + (size_t)MM * NN * CAP;

  k_detect<<<1, 64, 0, stream>>>(ei, flag);
  k_prep<<<(NN + 63) / 64, 256, 0, stream>>>(x_l, Wl, bl, Wc, bc, l, beta, deg);
  k_scatter<<<(MM * EE + 255) / 256, 256, 0, stream>>>(ei, flag, deg, lst);
  k_agg<<<(NN * 16 + 255) / 256, 256, 0, stream>>>(l, beta, deg, lst, attn_l, sharpen, out);
}